// Round 2
// baseline (1821.100 us; speedup 1.0000x reference)
//
#include <hip/hip_runtime.h>

// B=64,K=64 -> 4096 (b,k) blocks; L=128 rows; D=128; H=256; 6 layers.
// fp32 tiles stored XOR-swizzled on 16B chunks: chunk' = chunk ^ (row&7)
#define FID4(r,c4) ((r)*128 + ((((c4) ^ ((r)&7))) << 2))              // float4 chunk addr (dwords)
#define FIDS(r,c)  ((r)*128 + (((((c)>>2) ^ ((r)&7))) << 2) + ((c)&3)) // scalar float addr

typedef __attribute__((ext_vector_type(8))) short bf16x8;
typedef __attribute__((ext_vector_type(4))) float f32x4;

__device__ __forceinline__ unsigned short f2bf(float f){   // RNE float->bf16 bits
    unsigned u = __float_as_uint(f);
    u += 0x7fffu + ((u >> 16) & 1u);
    return (unsigned short)(u >> 16);
}
__device__ __forceinline__ float bf2f(unsigned short b){
    return __uint_as_float(((unsigned)b) << 16);
}
__device__ __forceinline__ float tanh_fast(float x){
    float e = __expf(2.0f * x);
    return 1.0f - 2.0f / (e + 1.0f);
}

__global__ void pack_w_kernel(const float* __restrict__ Ws,
                              unsigned short* __restrict__ Wh,
                              unsigned short* __restrict__ Wl){
    int i = blockIdx.x * 256 + threadIdx.x;   // 6*256*256 = 393216 exact
    float w = Ws[i];
    unsigned short h = f2bf(w);
    Wh[i] = h;
    Wl[i] = f2bf(w - bf2f(h));
}

__global__ __launch_bounds__(512, 2)
void fused_mlp_som(const float* __restrict__ ctx_in,   // (4096, 2, 128, 128) f32
                   const float* __restrict__ bs,       // (6,256)
                   const float* __restrict__ Wout,     // (256)
                   const float* __restrict__ bout,     // (1)
                   const unsigned short* __restrict__ Wh,
                   const unsigned short* __restrict__ Wl,
                   float* __restrict__ out)            // (4096)
{
    extern __shared__ char smem[];
    float* ctxS   = (float*)smem;                 // [128][128] f32, swizzled (64 KB)
    float* entS   = ctxS + 128*128;               // [128][128] f32, swizzled (64 KB)
    float* inv_cn = entS + 128*128;               // [128]
    float* inv_en = inv_cn + 128;                 // [128]
    int*   idxm   = (int*)(inv_en + 128);         // [128]
    float* redbuf = (float*)(idxm + 128);         // [8]
    // Phase-2 aliases (after barrier): swizzled bf16 hi/lo x-buffer (128 KB)
    unsigned short* xh = (unsigned short*)smem;   // [128][256]
    unsigned short* xl = xh + 128*256;

    const int tid  = threadIdx.x;
    const int lane = tid & 63;
    const int bk   = blockIdx.x;

    // ---------------- stage ctx/ent -> LDS (swizzled float4 writes) ----------------
    const float4* gbase = (const float4*)(ctx_in + (size_t)bk * (2*128*128));
    #pragma unroll
    for (int it = 0; it < 8; ++it){
        int fi = tid + 512*it;           // 0..4095 float4s per 64KB tile
        int r  = fi >> 5;
        int c4 = fi & 31;
        float4 v = gbase[fi];
        *(float4*)&ctxS[FID4(r,c4)] = v;
        float4 e = gbase[fi + 4096];
        *(float4*)&entS[FID4(r,c4)] = e;
    }
    __syncthreads();

    // ---------------- row norms ----------------
    {
        int hf = tid & 1;
        int r  = (tid >> 1) & 127;
        const float* tile = (tid < 256) ? ctxS : entS;
        float s = 0.f;
        #pragma unroll
        for (int u = 0; u < 16; ++u){
            float4 v = *(const float4*)&tile[FID4(r, 16*hf + u)];
            s = fmaf(v.x, v.x, s); s = fmaf(v.y, v.y, s);
            s = fmaf(v.z, v.z, s); s = fmaf(v.w, v.w, s);
        }
        s += __shfl_xor(s, 1);
        if (hf == 0){
            float inv = 1.0f / sqrtf(s);
            if (tid < 256) inv_cn[r] = inv; else inv_en[r] = inv;
        }
    }
    __syncthreads();

    // ---------------- similarity (fp32 VALU) + argmax ----------------
    {
        const int ti = tid >> 5;
        const int tj = tid & 31;
        const int l0 = ti * 8;
        float acc[8][4];
        #pragma unroll
        for (int i = 0; i < 8; ++i)
            #pragma unroll
            for (int j = 0; j < 4; ++j) acc[i][j] = 0.f;

        for (int kc = 0; kc < 32; ++kc){
            float4 e0 = *(const float4*)&entS[FID4(tj     , kc)];
            float4 e1 = *(const float4*)&entS[FID4(tj + 32, kc)];
            float4 e2 = *(const float4*)&entS[FID4(tj + 64, kc)];
            float4 e3 = *(const float4*)&entS[FID4(tj + 96, kc)];
            #pragma unroll
            for (int i = 0; i < 8; ++i){
                float4 a = *(const float4*)&ctxS[FID4(l0+i, kc)];
                acc[i][0] = fmaf(a.x,e0.x,acc[i][0]); acc[i][0] = fmaf(a.y,e0.y,acc[i][0]);
                acc[i][0] = fmaf(a.z,e0.z,acc[i][0]); acc[i][0] = fmaf(a.w,e0.w,acc[i][0]);
                acc[i][1] = fmaf(a.x,e1.x,acc[i][1]); acc[i][1] = fmaf(a.y,e1.y,acc[i][1]);
                acc[i][1] = fmaf(a.z,e1.z,acc[i][1]); acc[i][1] = fmaf(a.w,e1.w,acc[i][1]);
                acc[i][2] = fmaf(a.x,e2.x,acc[i][2]); acc[i][2] = fmaf(a.y,e2.y,acc[i][2]);
                acc[i][2] = fmaf(a.z,e2.z,acc[i][2]); acc[i][2] = fmaf(a.w,e2.w,acc[i][2]);
                acc[i][3] = fmaf(a.x,e3.x,acc[i][3]); acc[i][3] = fmaf(a.y,e3.y,acc[i][3]);
                acc[i][3] = fmaf(a.z,e3.z,acc[i][3]); acc[i][3] = fmaf(a.w,e3.w,acc[i][3]);
            }
        }
        #pragma unroll
        for (int i = 0; i < 8; ++i){
            float best = -1e38f; int bi = 0;
            #pragma unroll
            for (int j = 0; j < 4; ++j){
                int m = tj + 32*j;
                float v = acc[i][j] * inv_en[m];
                if (v > best || (v == best && m < bi)){ best = v; bi = m; }
            }
            #pragma unroll
            for (int s = 1; s < 32; s <<= 1){
                float ov = __shfl_xor(best, s);
                int   oi = __shfl_xor(bi,   s);
                if (ov > best || (ov == best && oi < bi)){ best = ov; bi = oi; }
            }
            if (tj == 0) idxm[l0 + i] = bi;
        }
    }
    __syncthreads();

    // ---------------- build x0 = [ctx_n | ent_n[idx]] bf16 hi/lo, XOR-swizzled ----------------
    {
        const int c    = tid & 255;
        const int half = tid >> 8;
        unsigned pk[64];
        #pragma unroll
        for (int r = 0; r < 64; ++r){
            int l = half*64 + r;
            float v;
            if (c < 128){
                v = ctxS[FIDS(l, c)] * inv_cn[l];
            } else {
                int mi = idxm[l];
                v = entS[FIDS(mi, c-128)] * inv_en[mi];
            }
            unsigned short h  = f2bf(v);
            unsigned short lo = f2bf(v - bf2f(h));
            pk[r] = (unsigned)h | ((unsigned)lo << 16);
        }
        __syncthreads();
        #pragma unroll
        for (int r = 0; r < 64; ++r){
            int l  = half*64 + r;
            int ci = (((2*c) ^ ((l & 7) << 4)) >> 1);
            xh[l*256 + ci] = (unsigned short)(pk[r] & 0xffffu);
            xl[l*256 + ci] = (unsigned short)(pk[r] >> 16);
        }
    }
    __syncthreads();

    // ---------------- 6-layer MLP: split-bf16 3-product MFMA ----------------
    // N-split-8 (W-read-minimal): wave wv owns output cols [32wv, 32wv+32).
    const int wv    = tid >> 6;
    const int lan15 = lane & 15;
    const int lq    = lane >> 4;
    const int n0    = 32*wv + lan15;
    const int n1    = n0 + 16;
    const int kb    = 8*lq;

    #pragma unroll 1
    for (int layer = 0; layer < 6; ++layer){
        const unsigned short* WhL = Wh + layer*(256*256);
        const unsigned short* WlL = Wl + layer*(256*256);
        f32x4 acc[8][2];
        #pragma unroll
        for (int mt = 0; mt < 8; ++mt){
            acc[mt][0] = (f32x4){0.f,0.f,0.f,0.f};
            acc[mt][1] = (f32x4){0.f,0.f,0.f,0.f};
        }
        bf16x8 bh0 = *(const bf16x8*)&WhL[n0*256 + kb];
        bf16x8 bl0 = *(const bf16x8*)&WlL[n0*256 + kb];
        bf16x8 bh1 = *(const bf16x8*)&WhL[n1*256 + kb];
        bf16x8 bl1 = *(const bf16x8*)&WlL[n1*256 + kb];
        #pragma unroll 2
        for (int ks = 0; ks < 8; ++ks){
            const int k0  = 32*ks + kb;
            const int k0n = 32*((ks+1)&7) + kb;
            // batch ALL A-frag reads for this ks first (one lgkm wait point,
            // LDS pipeline stays full, MFMA burst uninterrupted)
            bf16x8 ah[8], al[8];
            #pragma unroll
            for (int mt = 0; mt < 8; ++mt){
                int arow = 16*mt + lan15;
                int ai = arow*256 + (((2*k0) ^ ((arow&7)<<4)) >> 1);
                ah[mt] = *(const bf16x8*)&xh[ai];
                al[mt] = *(const bf16x8*)&xl[ai];
            }
            // prefetch next ks B-frags (L2-hot W)
            bf16x8 nh0 = *(const bf16x8*)&WhL[n0*256 + k0n];
            bf16x8 nl0 = *(const bf16x8*)&WlL[n0*256 + k0n];
            bf16x8 nh1 = *(const bf16x8*)&WhL[n1*256 + k0n];
            bf16x8 nl1 = *(const bf16x8*)&WlL[n1*256 + k0n];
            #pragma unroll
            for (int mt = 0; mt < 8; ++mt){
                acc[mt][0] = __builtin_amdgcn_mfma_f32_16x16x32_bf16(ah[mt], bh0, acc[mt][0], 0,0,0);
                acc[mt][1] = __builtin_amdgcn_mfma_f32_16x16x32_bf16(ah[mt], bh1, acc[mt][1], 0,0,0);
                acc[mt][0] = __builtin_amdgcn_mfma_f32_16x16x32_bf16(ah[mt], bl0, acc[mt][0], 0,0,0);
                acc[mt][1] = __builtin_amdgcn_mfma_f32_16x16x32_bf16(ah[mt], bl1, acc[mt][1], 0,0,0);
                acc[mt][0] = __builtin_amdgcn_mfma_f32_16x16x32_bf16(al[mt], bh0, acc[mt][0], 0,0,0);
                acc[mt][1] = __builtin_amdgcn_mfma_f32_16x16x32_bf16(al[mt], bh1, acc[mt][1], 0,0,0);
            }
            bh0 = nh0; bl0 = nl0; bh1 = nh1; bl1 = nl1;
        }
        __syncthreads();   // all waves done reading xh/xl

        if (layer < 5){
            float bias0 = bs[layer*256 + n0];
            float bias1 = bs[layer*256 + n1];
            #pragma unroll
            for (int mt = 0; mt < 8; ++mt){
                #pragma unroll
                for (int r = 0; r < 4; ++r){
                    int row = 16*mt + 4*lq + r;      // C/D: col=lane&15, row=(lane>>4)*4+reg
                    int sw  = (row & 7) << 4;
                    float t0 = tanh_fast(acc[mt][0][r] + bias0);
                    float t1 = tanh_fast(acc[mt][1][r] + bias1);
                    unsigned short h0 = f2bf(t0);
                    unsigned short o0 = f2bf(t0 - bf2f(h0));
                    unsigned short h1 = f2bf(t1);
                    unsigned short o1 = f2bf(t1 - bf2f(h1));
                    int ci0 = (((2*n0) ^ sw) >> 1);
                    int ci1 = (((2*n1) ^ sw) >> 1);
                    xh[row*256 + ci0] = h0;  xl[row*256 + ci0] = o0;
                    xh[row*256 + ci1] = h1;  xl[row*256 + ci1] = o1;
                }
            }
            __syncthreads();
        } else {
            float bias0 = bs[5*256 + n0];
            float bias1 = bs[5*256 + n1];
            float w0 = Wout[n0];
            float w1 = Wout[n1];
            float part = 0.f;
            #pragma unroll
            for (int mt = 0; mt < 8; ++mt){
                #pragma unroll
                for (int r = 0; r < 4; ++r){
                    part = fmaf(tanh_fast(acc[mt][0][r] + bias0), w0, part);
                    part = fmaf(tanh_fast(acc[mt][1][r] + bias1), w1, part);
                }
            }
            #pragma unroll
            for (int s = 1; s < 64; s <<= 1) part += __shfl_xor(part, s);
            if (lane == 0) redbuf[wv] = part;
            __syncthreads();
            if (tid == 0){
                float s = 0.f;
                #pragma unroll
                for (int i = 0; i < 8; ++i) s += redbuf[i];
                out[bk] = s + 128.0f * bout[0];
            }
        }
    }
}

extern "C" void kernel_launch(void* const* d_in, const int* in_sizes, int n_in,
                              void* d_out, int out_size, void* d_ws, size_t ws_size,
                              hipStream_t stream)
{
    (void)in_sizes; (void)n_in; (void)out_size; (void)ws_size;
    const float* ctx  = (const float*)d_in[0];
    const float* Ws   = (const float*)d_in[1];
    const float* bs   = (const float*)d_in[2];
    const float* Wout = (const float*)d_in[3];
    const float* bout = (const float*)d_in[4];
    float* out = (float*)d_out;

    unsigned short* Wh = (unsigned short*)d_ws;          // 6*256*256 bf16 hi plane
    unsigned short* Wl = Wh + 6*256*256;                 // lo plane (1.5 MB total)

    pack_w_kernel<<<dim3(1536), dim3(256), 0, stream>>>(Ws, Wh, Wl);

    const int smem_bytes = 2*128*128*4 + 128*4 + 128*4 + 128*4 + 8*4;  // 132640 B
    hipFuncSetAttribute(reinterpret_cast<const void*>(fused_mlp_som),
                        hipFuncAttributeMaxDynamicSharedMemorySize, smem_bytes);
    fused_mlp_som<<<dim3(4096), dim3(512), smem_bytes, stream>>>(ctx, bs, Wout, bout, Wh, Wl, out);
}

// Round 3
// 1667.803 us; speedup vs baseline: 1.0919x; 1.0919x over previous
//
#include <hip/hip_runtime.h>

// B=64,K=64 -> 4096 (b,k) blocks; L=128 rows; D=128; H=256; 6 layers.
// Phase-1 fp32 tiles XOR-swizzled on 16B chunks: chunk' = chunk ^ (row&7)
#define FID4(r,c4) ((r)*128 + ((((c4) ^ ((r)&7))) << 2))               // float4 chunk addr (dwords)
#define FIDS(r,c)  ((r)*128 + (((((c)>>2) ^ ((r)&7))) << 2) + ((c)&3))  // scalar float addr
// Phase-2 fp16 x-buffer [128][256], swizzled on 8-elem (16B) chunks
#define XIDX(r,c)  ((r)*256 + (((((c)>>3) ^ ((r)&7))) << 3) + ((c)&7))

typedef _Float16 half_t;
typedef __attribute__((ext_vector_type(8))) _Float16 f16x8;
typedef __attribute__((ext_vector_type(4))) float f32x4;

__device__ __forceinline__ float tanh_fast(float x){
    float e = __expf(2.0f * x);
    return 1.0f - 2.0f / (e + 1.0f);
}

// W -> fp16 hi + fp16 scaled-lo:  W ~= Wh + Wl*2^-10  (Wl kept in fp16 normal range)
__global__ void pack_w_kernel(const float* __restrict__ Ws,
                              half_t* __restrict__ Wh,
                              half_t* __restrict__ Wl){
    int i = blockIdx.x * 256 + threadIdx.x;   // 6*256*256 = 393216 exact
    float w = Ws[i];
    half_t h = (half_t)w;                     // v_cvt_f16_f32, RNE
    Wh[i] = h;
    Wl[i] = (half_t)((w - (float)h) * 1024.0f);
}

__global__ __launch_bounds__(512)
__attribute__((amdgpu_waves_per_eu(2, 2)))   // LDS caps us at 1 WG/CU = 2 waves/SIMD; give allocator the full 256-reg budget
void fused_mlp_som(const float* __restrict__ ctx_in,   // (4096, 2, 128, 128) f32
                   const float* __restrict__ bs,       // (6,256)
                   const float* __restrict__ Wout,     // (256)
                   const float* __restrict__ bout,     // (1)
                   const half_t* __restrict__ Wh,
                   const half_t* __restrict__ Wl,
                   float* __restrict__ out)            // (4096)
{
    extern __shared__ char smem[];
    float* ctxS   = (float*)smem;                 // [128][128] f32, swizzled (64 KB)
    float* entS   = ctxS + 128*128;               // [128][128] f32, swizzled (64 KB)
    float* inv_cn = entS + 128*128;               // [128]
    float* inv_en = inv_cn + 128;                 // [128]
    int*   idxm   = (int*)(inv_en + 128);         // [128]
    float* redbuf = (float*)(idxm + 128);         // [8]
    // Phase-2 alias (after barrier): fp16 x-buffer [128][256] = 64 KB over ctxS
    half_t* xf = (half_t*)smem;

    const int tid  = threadIdx.x;
    const int lane = tid & 63;
    const int bk   = blockIdx.x;

    // ---------------- stage ctx/ent -> LDS (swizzled float4 writes) ----------------
    const float4* gbase = (const float4*)(ctx_in + (size_t)bk * (2*128*128));
    #pragma unroll
    for (int it = 0; it < 8; ++it){
        int fi = tid + 512*it;           // 0..4095 float4s per 64KB tile
        int r  = fi >> 5;
        int c4 = fi & 31;
        float4 v = gbase[fi];
        *(float4*)&ctxS[FID4(r,c4)] = v;
        float4 e = gbase[fi + 4096];
        *(float4*)&entS[FID4(r,c4)] = e;
    }
    __syncthreads();

    // ---------------- row norms (bit-identical to R1/R2) ----------------
    {
        int hf = tid & 1;
        int r  = (tid >> 1) & 127;
        const float* tile = (tid < 256) ? ctxS : entS;
        float s = 0.f;
        #pragma unroll
        for (int u = 0; u < 16; ++u){
            float4 v = *(const float4*)&tile[FID4(r, 16*hf + u)];
            s = fmaf(v.x, v.x, s); s = fmaf(v.y, v.y, s);
            s = fmaf(v.z, v.z, s); s = fmaf(v.w, v.w, s);
        }
        s += __shfl_xor(s, 1);
        if (hf == 0){
            float inv = 1.0f / sqrtf(s);
            if (tid < 256) inv_cn[r] = inv; else inv_en[r] = inv;
        }
    }
    __syncthreads();

    // ---------------- similarity (fp32 VALU) + argmax (bit-identical) ----------------
    {
        const int ti = tid >> 5;
        const int tj = tid & 31;
        const int l0 = ti * 8;
        float acc[8][4];
        #pragma unroll
        for (int i = 0; i < 8; ++i)
            #pragma unroll
            for (int j = 0; j < 4; ++j) acc[i][j] = 0.f;

        for (int kc = 0; kc < 32; ++kc){
            float4 e0 = *(const float4*)&entS[FID4(tj     , kc)];
            float4 e1 = *(const float4*)&entS[FID4(tj + 32, kc)];
            float4 e2 = *(const float4*)&entS[FID4(tj + 64, kc)];
            float4 e3 = *(const float4*)&entS[FID4(tj + 96, kc)];
            #pragma unroll
            for (int i = 0; i < 8; ++i){
                float4 a = *(const float4*)&ctxS[FID4(l0+i, kc)];
                acc[i][0] = fmaf(a.x,e0.x,acc[i][0]); acc[i][0] = fmaf(a.y,e0.y,acc[i][0]);
                acc[i][0] = fmaf(a.z,e0.z,acc[i][0]); acc[i][0] = fmaf(a.w,e0.w,acc[i][0]);
                acc[i][1] = fmaf(a.x,e1.x,acc[i][1]); acc[i][1] = fmaf(a.y,e1.y,acc[i][1]);
                acc[i][1] = fmaf(a.z,e1.z,acc[i][1]); acc[i][1] = fmaf(a.w,e1.w,acc[i][1]);
                acc[i][2] = fmaf(a.x,e2.x,acc[i][2]); acc[i][2] = fmaf(a.y,e2.y,acc[i][2]);
                acc[i][2] = fmaf(a.z,e2.z,acc[i][2]); acc[i][2] = fmaf(a.w,e2.w,acc[i][2]);
                acc[i][3] = fmaf(a.x,e3.x,acc[i][3]); acc[i][3] = fmaf(a.y,e3.y,acc[i][3]);
                acc[i][3] = fmaf(a.z,e3.z,acc[i][3]); acc[i][3] = fmaf(a.w,e3.w,acc[i][3]);
            }
        }
        #pragma unroll
        for (int i = 0; i < 8; ++i){
            float best = -1e38f; int bi = 0;
            #pragma unroll
            for (int j = 0; j < 4; ++j){
                int m = tj + 32*j;
                float v = acc[i][j] * inv_en[m];
                if (v > best || (v == best && m < bi)){ best = v; bi = m; }
            }
            #pragma unroll
            for (int s = 1; s < 32; s <<= 1){
                float ov = __shfl_xor(best, s);
                int   oi = __shfl_xor(bi,   s);
                if (ov > best || (ov == best && oi < bi)){ best = ov; bi = oi; }
            }
            if (tj == 0) idxm[l0 + i] = bi;
        }
    }
    __syncthreads();

    // ---------------- build x0 = [ctx_n | ent_n[idx]] as fp16, XOR-swizzled ----------------
    {
        const int c  = tid & 255;
        const int hb = tid >> 8;
        half_t pk[64];
        #pragma unroll
        for (int r = 0; r < 64; ++r){
            int l = hb*64 + r;
            float v;
            if (c < 128){
                v = ctxS[FIDS(l, c)] * inv_cn[l];
            } else {
                int mi = idxm[l];
                v = entS[FIDS(mi, c-128)] * inv_en[mi];
            }
            pk[r] = (half_t)v;
        }
        __syncthreads();
        #pragma unroll
        for (int r = 0; r < 64; ++r){
            int l = hb*64 + r;
            xf[XIDX(l, c)] = pk[r];
        }
    }
    __syncthreads();

    // ---------------- 6-layer MLP: fp16 2-product MFMA (x fp16, W = Wh + Wl*2^-10) ----------------
    // N-split-8 (W-read-minimal): wave wv owns output cols [32wv, 32wv+32).
    const int wv    = tid >> 6;
    const int lan15 = lane & 15;
    const int lq    = lane >> 4;
    const int n0    = 32*wv + lan15;
    const int n1    = n0 + 16;
    const int bno0  = n0 * 256;
    const int bno1  = n1 * 256;
    const int kb    = 8*lq;

    #pragma unroll 1
    for (int layer = 0; layer < 6; ++layer){
        const half_t* WhL = Wh + layer*(256*256);
        const half_t* WlL = Wl + layer*(256*256);
        f32x4 accH[8][2], accL[8][2];
        #pragma unroll
        for (int mt = 0; mt < 8; ++mt){
            accH[mt][0] = (f32x4){0.f,0.f,0.f,0.f};
            accH[mt][1] = (f32x4){0.f,0.f,0.f,0.f};
            accL[mt][0] = (f32x4){0.f,0.f,0.f,0.f};
            accL[mt][1] = (f32x4){0.f,0.f,0.f,0.f};
        }
        f16x8 bh0 = *(const f16x8*)&WhL[bno0 + kb];
        f16x8 bl0 = *(const f16x8*)&WlL[bno0 + kb];
        f16x8 bh1 = *(const f16x8*)&WhL[bno1 + kb];
        f16x8 bl1 = *(const f16x8*)&WlL[bno1 + kb];
        #pragma unroll 1
        for (int ks = 0; ks < 8; ++ks){
            const int kn = 32*((ks+1)&7) + kb;
            // batched A reads: one vaddr, 8 mt via immediate offsets (swizzle term is mt-invariant)
            const int aoff = (((4*ks + lq) ^ (lan15 & 7)) << 3);
            f16x8 a[8];
            #pragma unroll
            for (int mt = 0; mt < 8; ++mt)
                a[mt] = *(const f16x8*)&xf[(16*mt + lan15)*256 + aoff];
            // prefetch next-ks B frags (L2-hot W)
            f16x8 nh0 = *(const f16x8*)&WhL[bno0 + kn];
            f16x8 nl0 = *(const f16x8*)&WlL[bno0 + kn];
            f16x8 nh1 = *(const f16x8*)&WhL[bno1 + kn];
            f16x8 nl1 = *(const f16x8*)&WlL[bno1 + kn];
            #pragma unroll
            for (int mt = 0; mt < 8; ++mt){
                accH[mt][0] = __builtin_amdgcn_mfma_f32_16x16x32_f16(a[mt], bh0, accH[mt][0], 0,0,0);
                accH[mt][1] = __builtin_amdgcn_mfma_f32_16x16x32_f16(a[mt], bh1, accH[mt][1], 0,0,0);
                accL[mt][0] = __builtin_amdgcn_mfma_f32_16x16x32_f16(a[mt], bl0, accL[mt][0], 0,0,0);
                accL[mt][1] = __builtin_amdgcn_mfma_f32_16x16x32_f16(a[mt], bl1, accL[mt][1], 0,0,0);
            }
            bh0 = nh0; bl0 = nl0; bh1 = nh1; bl1 = nl1;
        }
        __syncthreads();   // all waves done reading xf

        if (layer < 5){
            float bias0 = bs[layer*256 + n0];
            float bias1 = bs[layer*256 + n1];
            #pragma unroll
            for (int mt = 0; mt < 8; ++mt){
                #pragma unroll
                for (int r = 0; r < 4; ++r){
                    int row = 16*mt + 4*lq + r;      // C/D: col=lane&15, row=(lane>>4)*4+reg
                    float h0 = accH[mt][0][r] + accL[mt][0][r]*(1.0f/1024.0f) + bias0;
                    float h1 = accH[mt][1][r] + accL[mt][1][r]*(1.0f/1024.0f) + bias1;
                    xf[XIDX(row, n0)] = (half_t)tanh_fast(h0);
                    xf[XIDX(row, n1)] = (half_t)tanh_fast(h1);
                }
            }
            __syncthreads();
        } else {
            float bias0 = bs[5*256 + n0];
            float bias1 = bs[5*256 + n1];
            float w0 = Wout[n0];
            float w1 = Wout[n1];
            float part = 0.f;
            #pragma unroll
            for (int mt = 0; mt < 8; ++mt){
                #pragma unroll
                for (int r = 0; r < 4; ++r){
                    float h0 = accH[mt][0][r] + accL[mt][0][r]*(1.0f/1024.0f) + bias0;
                    float h1 = accH[mt][1][r] + accL[mt][1][r]*(1.0f/1024.0f) + bias1;
                    part = fmaf(tanh_fast(h0), w0, part);
                    part = fmaf(tanh_fast(h1), w1, part);
                }
            }
            #pragma unroll
            for (int s = 1; s < 64; s <<= 1) part += __shfl_xor(part, s);
            if (lane == 0) redbuf[wv] = part;
            __syncthreads();
            if (tid == 0){
                float s = 0.f;
                #pragma unroll
                for (int i = 0; i < 8; ++i) s += redbuf[i];
                out[bk] = s + 128.0f * bout[0];
            }
        }
    }
}

extern "C" void kernel_launch(void* const* d_in, const int* in_sizes, int n_in,
                              void* d_out, int out_size, void* d_ws, size_t ws_size,
                              hipStream_t stream)
{
    (void)in_sizes; (void)n_in; (void)out_size; (void)ws_size;
    const float* ctx  = (const float*)d_in[0];
    const float* Ws   = (const float*)d_in[1];
    const float* bs   = (const float*)d_in[2];
    const float* Wout = (const float*)d_in[3];
    const float* bout = (const float*)d_in[4];
    float* out = (float*)d_out;

    half_t* Wh = (half_t*)d_ws;               // 6*256*256 fp16 hi plane
    half_t* Wl = Wh + 6*256*256;              // scaled lo plane (1.5 MB total)

    pack_w_kernel<<<dim3(1536), dim3(256), 0, stream>>>(Ws, Wh, Wl);

    const int smem_bytes = 2*128*128*4 + 128*4 + 128*4 + 128*4 + 8*4;  // 132640 B
    hipFuncSetAttribute(reinterpret_cast<const void*>(fused_mlp_som),
                        hipFuncAttributeMaxDynamicSharedMemorySize, smem_bytes);
    fused_mlp_som<<<dim3(4096), dim3(512), smem_bytes, stream>>>(ctx, bs, Wout, bout, Wh, Wl, out);
}